// Round 16
// baseline (816.100 us; speedup 1.0000x reference)
//
#include <hip/hip_runtime.h>
#include <hip/hip_bf16.h>

typedef _Float16 f16;
typedef _Float16 f16x8 __attribute__((ext_vector_type(8)));
typedef _Float16 f16x4 __attribute__((ext_vector_type(4)));
typedef _Float16 f16x2 __attribute__((ext_vector_type(2)));
typedef float f32x4 __attribute__((ext_vector_type(4)));
typedef unsigned long long ull;

#define B_ 64
#define T_ 32
#define L_ 49
#define F_ 512
#define H_ 512
#define A_ 256
#define E_ 256
#define V_ 32000
#define G4 2048
#define NG 64       // recurrent-gemm blocks (8 hidden = 32 permuted cols, Whh+Wih2)
#define NLOG 125    // logit blocks (256 cols each), t-chunk = 2, lazy W_out transpose
#define SLOT 16

#define ALOAD32(p)     __hip_atomic_load((const unsigned*)(p), __ATOMIC_RELAXED, __HIP_MEMORY_SCOPE_AGENT)
#define ASTORE32(p, v) __hip_atomic_store((unsigned*)(p), (v), __ATOMIC_RELAXED, __HIP_MEMORY_SCOPE_AGENT)
#define ASTORE64(p, v) __hip_atomic_store((ull*)(p), (v), __ATOMIC_RELAXED, __HIP_MEMORY_SCOPE_AGENT)

#if defined(__has_builtin)
#if __has_builtin(__builtin_amdgcn_fdot2)
#define HAS_FDOT2 1
#endif
#endif

// ================================================================ k_prep: embP GEMM only
// embP = gather(embedding, caption) @ W_ih[:E,:] + b_ih + b_hh, gate-permuted f16.
// Separate dispatch: its interleaved output needs plain stores (kernel boundary
// provides cross-block visibility).
struct Smem128 { f16 As[128][40]; f16 Bs[128][40]; };

__global__ __launch_bounds__(256) void k_prep(
    const int* __restrict__ caption, const float* __restrict__ embedding,
    const float* __restrict__ W_ih,
    const float* __restrict__ b_ih, const float* __restrict__ b_hh,
    f16* __restrict__ embP) {
    __shared__ Smem128 sm;
    int tid = threadIdx.x;
    int mtiles = B_ * T_ / 128;
    int m0 = ((int)blockIdx.x % mtiles) * 128, n0 = ((int)blockIdx.x / mtiles) * 128;
    int lane = tid & 63, wave = tid >> 6;
    int wr = (wave >> 1) * 64, wc = (wave & 1) * 64;
    int frow = lane & 15, fk = (lane >> 4) * 8;
    int ra = tid >> 2, ka = (tid & 3) * 8;
    int kb = tid >> 3, nb = (tid & 7) * 16;
    int tok0 = caption[m0 + ra], tok1 = caption[m0 + 64 + ra];
    f32x4 acc[4][4];
#pragma unroll
    for (int i = 0; i < 4; ++i)
#pragma unroll
        for (int j = 0; j < 4; ++j) { acc[i][j][0]=0.f; acc[i][j][1]=0.f; acc[i][j][2]=0.f; acc[i][j][3]=0.f; }
    for (int k0 = 0; k0 < E_; k0 += 32) {
        float4 e00 = *(const float4*)&embedding[(size_t)tok0 * E_ + k0 + ka];
        float4 e01 = *(const float4*)&embedding[(size_t)tok0 * E_ + k0 + ka + 4];
        float4 e10 = *(const float4*)&embedding[(size_t)tok1 * E_ + k0 + ka];
        float4 e11 = *(const float4*)&embedding[(size_t)tok1 * E_ + k0 + ka + 4];
        const float* wrow = W_ih + (size_t)(k0 + kb) * G4 + n0 + nb;
        float4 w0 = *(const float4*)wrow;
        float4 w1 = *(const float4*)(wrow + 4);
        float4 w2 = *(const float4*)(wrow + 8);
        float4 w3 = *(const float4*)(wrow + 12);
        __syncthreads();
        {
            f16x8 a0 = {(f16)e00.x,(f16)e00.y,(f16)e00.z,(f16)e00.w,
                        (f16)e01.x,(f16)e01.y,(f16)e01.z,(f16)e01.w};
            f16x8 a1 = {(f16)e10.x,(f16)e10.y,(f16)e10.z,(f16)e10.w,
                        (f16)e11.x,(f16)e11.y,(f16)e11.z,(f16)e11.w};
            *(f16x8*)&sm.As[ra][ka] = a0;
            *(f16x8*)&sm.As[64 + ra][ka] = a1;
            float wv[16] = {w0.x,w0.y,w0.z,w0.w, w1.x,w1.y,w1.z,w1.w,
                            w2.x,w2.y,w2.z,w2.w, w3.x,w3.y,w3.z,w3.w};
#pragma unroll
            for (int j = 0; j < 16; ++j) sm.Bs[nb + j][kb] = (f16)wv[j];
        }
        __syncthreads();
        f16x8 av[4], bv[4];
#pragma unroll
        for (int i = 0; i < 4; ++i) {
            av[i] = *(f16x8*)&sm.As[wr + i * 16 + frow][fk];
            bv[i] = *(f16x8*)&sm.Bs[wc + i * 16 + frow][fk];
        }
#pragma unroll
        for (int mi = 0; mi < 4; ++mi)
#pragma unroll
            for (int ni = 0; ni < 4; ++ni)
                acc[mi][ni] = __builtin_amdgcn_mfma_f32_16x16x32_f16(av[mi], bv[ni], acc[mi][ni], 0, 0, 0);
    }
    int rq = (lane >> 4) * 4;
#pragma unroll
    for (int mi = 0; mi < 4; ++mi)
#pragma unroll
        for (int ni = 0; ni < 4; ++ni) {
            int cc = n0 + wc + ni * 16 + frow;
            float badd = b_ih[cc] + b_hh[cc];
#pragma unroll
            for (int rr2 = 0; rr2 < 4; ++rr2) {
                int rr = m0 + wr + mi * 16 + rq + rr2;
                embP[((size_t)rr * 512 + (cc & 511)) * 4 + (cc >> 9)] =
                    (f16)(acc[mi][ni][rr2] + badd);
            }
        }
}

// ================================================================ persistent kernel
struct GateSm {
    float fp[L_][A_];        // featproj (50 KB, computed in-block)
    unsigned fe[L_ * 256];   // feats as packed f16 pairs (50 KB)
    float mean[F_];          // 2 KB (init only)
    float ea[A_];
    float ws[A_];
    float sc[64];
    float alpha[64];
    unsigned hL[256];
};
struct GemmSm {
    f16 w[32][512];          // Whh slice, XOR-swizzled (32 KB)
    f16 w2[32][512];         // Wih2 slice (32 KB)
    union {
        f16 hs[64][512];     // h / ctx stage (64 KB, swizzled)
        f16 hwT16[64][40];
    } u;
};
struct LogSm { f16 hs[128][512]; };

__device__ __forceinline__ void wait_n(const unsigned* flags, int n, unsigned target) {
    int tid = threadIdx.x;
    if (tid < n) {
        const unsigned* p = flags + tid * SLOT;
        while (ALOAD32(p) < target) __builtin_amdgcn_s_sleep(1);
    }
    asm volatile("" ::: "memory");
    __syncthreads();
}
__device__ __forceinline__ void wait_n_slow(const unsigned* flags, int n, unsigned target) {
    int tid = threadIdx.x;
    if (tid < n) {
        const unsigned* p = flags + tid * SLOT;
        while (ALOAD32(p) < target) __builtin_amdgcn_s_sleep(8);
    }
    asm volatile("" ::: "memory");
    __syncthreads();
}

__device__ __forceinline__ float sigm(float x) { return 1.f / (1.f + __expf(-x)); }
__device__ __forceinline__ float tanh_f(float x) { return 1.f - 2.f / (1.f + __expf(2.f * x)); }

__global__ __launch_bounds__(256, 1) void k_steps(
    const float* __restrict__ W_hh, const float* __restrict__ W_ih,
    const float* __restrict__ W_hid, f16* __restrict__ Whidp,
    const float* __restrict__ image_feats,
    const float* __restrict__ W_feat, const float* __restrict__ b_feat,
    const float* __restrict__ W_init_h, const float* __restrict__ b_init_h,
    const float* __restrict__ W_init_c, const float* __restrict__ b_init_c,
    const float* __restrict__ b_hid,
    const float* __restrict__ W_score, const float* __restrict__ b_score,
    const f16* __restrict__ embP,
    f16* __restrict__ hslab, f16* __restrict__ ctxslab,
    f16* __restrict__ hwslab, f16* __restrict__ cwslab,
    const float* __restrict__ W_out, f16* __restrict__ WoutT,
    const float* __restrict__ b_out,
    float* __restrict__ preds, float* __restrict__ out_alpha,
    unsigned* __restrict__ gateflag, unsigned* __restrict__ ctxflag,
    unsigned* __restrict__ hwflag, unsigned* __restrict__ cwflag,
    unsigned* __restrict__ whidflag) {
    __shared__ __align__(16) char smraw[sizeof(LogSm)];
    int bid = blockIdx.x, tid = threadIdx.x;

    if (bid < 64) {
        // ======== gate block for batch b: self-contained init + attention + pointwise ====
        int b = bid;
        GateSm* S = (GateSm*)smraw;
        // stage feats[b] raw f32 -> packed f16 pairs
        {
            const float2* src = (const float2*)(image_feats + (size_t)b * L_ * F_);
            for (int i = tid; i < L_ * 256; i += 256) {
                float2 v = src[i];
                union { f16 h[2]; unsigned u; } pk;
                pk.h[0] = (f16)v.x; pk.h[1] = (f16)v.y;
                S->fe[i] = pk.u;
            }
        }
        S->ws[tid] = W_score[tid];
        float bhid_r = b_hid[tid];
        float bsc = b_score[0];
        __syncthreads();
        // featproj in-block: fp[l][tid], 7 groups of 7 rows
        {
            float bf = b_feat[tid];
            for (int lt = 0; lt < 7; ++lt) {
                float acc[7] = {0.f,0.f,0.f,0.f,0.f,0.f,0.f};
                for (int k2 = 0; k2 < 256; ++k2) {
                    float w0 = W_feat[(size_t)(2 * k2) * A_ + tid];
                    float w1 = W_feat[(size_t)(2 * k2 + 1) * A_ + tid];
#pragma unroll
                    for (int j = 0; j < 7; ++j) {
                        union { unsigned u; f16x2 v; } fv;
                        fv.u = S->fe[(lt * 7 + j) * 256 + k2];
                        acc[j] += w0 * (float)fv.v.x + w1 * (float)fv.v.y;
                    }
                }
#pragma unroll
                for (int j = 0; j < 7; ++j) S->fp[lt * 7 + j][tid] = acc[j] + bf;
            }
        }
        // mean over l
        {
            float m0 = 0.f, m1 = 0.f;
#pragma unroll 7
            for (int l = 0; l < L_; ++l) {
                union { unsigned u; f16x2 v; } fv;
                fv.u = S->fe[l * 256 + tid];
                m0 += (float)fv.v.x; m1 += (float)fv.v.y;
            }
            S->mean[2 * tid]     = m0 * (1.f / 49.f);
            S->mean[2 * tid + 1] = m1 * (1.f / 49.f);
        }
        __syncthreads();
        // h0/c0 for cols j0 = 2tid, j0+1
        int j0 = 2 * tid;
        float cs0, cs1;
        {
            float h0a = b_init_h[j0], h0b = b_init_h[j0 + 1];
            float c0a = b_init_c[j0], c0b = b_init_c[j0 + 1];
            for (int k = 0; k < F_; ++k) {
                float m = S->mean[k];
                float2 wh = *(const float2*)&W_init_h[(size_t)k * H_ + j0];
                float2 wc = *(const float2*)&W_init_c[(size_t)k * H_ + j0];
                h0a += m * wh.x; h0b += m * wh.y;
                c0a += m * wc.x; c0b += m * wc.y;
            }
            cs0 = c0a; cs1 = c0b;
            union { f16 h[2]; unsigned u; } pk;
            pk.h[0] = (f16)h0a; pk.h[1] = (f16)h0b;
            S->hL[tid] = pk.u;
            ASTORE32((unsigned*)hslab + (size_t)b * 256 + tid, pk.u);
        }
        __syncthreads();   // drains vmcnt: h0 sc1 stores acked; hL visible
        if (tid == 0) ASTORE32(&gateflag[b * SLOT], 1u);
        // wait Whidp packed by gemm blocks (one-time)
        wait_n(whidflag, NG, 1u);
        const f16x4* wp4 = (const f16x4*)Whidp;
        int wv = tid >> 6, ln = tid & 63;

        for (int t = 0; t < T_; ++t) {
            // ---- ea = h @ W_hid + b_hid ----
            {
                float acc = bhid_r;
#pragma unroll 16
                for (int k4 = 0; k4 < 128; ++k4) {
                    union { f16x4 v; f16x2 p[2]; } w;
                    w.v = wp4[(size_t)k4 * 256 + tid];
                    union { unsigned u; f16x2 v; } h0, h1;
                    h0.u = S->hL[2 * k4];
                    h1.u = S->hL[2 * k4 + 1];
#ifdef HAS_FDOT2
                    acc = __builtin_amdgcn_fdot2(w.p[0], h0.v, acc, false);
                    acc = __builtin_amdgcn_fdot2(w.p[1], h1.v, acc, false);
#else
                    acc += (float)w.p[0].x * (float)h0.v.x + (float)w.p[0].y * (float)h0.v.y;
                    acc += (float)w.p[1].x * (float)h1.v.x + (float)w.p[1].y * (float)h1.v.y;
#endif
                }
                S->ea[tid] = acc;
            }
            __syncthreads();
            // ---- scores ----
            for (int l = wv; l < L_; l += 4) {
                float p = 0.f;
#pragma unroll
                for (int q = 0; q < 4; ++q) {
                    int j = ln + q * 64;
                    p += tanh_f(S->fp[l][j] + S->ea[j]) * S->ws[j];
                }
#pragma unroll
                for (int off = 32; off > 0; off >>= 1) p += __shfl_xor(p, off);
                if (ln == 0) S->sc[l] = p;
            }
            __syncthreads();
            // ---- softmax (wave 0) ----
            if (tid < 64) {
                float v = (tid < L_) ? S->sc[tid] + bsc : -3.4e38f;
                float m = v;
#pragma unroll
                for (int off = 32; off > 0; off >>= 1) m = fmaxf(m, __shfl_xor(m, off));
                float e = (tid < L_) ? __expf(v - m) : 0.f;
                float s = e;
#pragma unroll
                for (int off = 32; off > 0; off >>= 1) s += __shfl_xor(s, off);
                if (tid < L_) {
                    float al = e / s;
                    S->alpha[tid] = al;
                    out_alpha[((size_t)b * T_ + t) * L_ + tid] = al;
                }
            }
            __syncthreads();
            // ---- ctx publish ----
            {
                float c0 = 0.f, c1 = 0.f;
#pragma unroll 7
                for (int l = 0; l < L_; ++l) {
                    float a = S->alpha[l];
                    union { unsigned u; f16x2 v; } fv;
                    fv.u = S->fe[l * 256 + tid];
                    c0 += a * (float)fv.v.x;
                    c1 += a * (float)fv.v.y;
                }
                union { f16 h[2]; unsigned u; } pk;
                pk.h[0] = (f16)c0; pk.h[1] = (f16)c1;
                ASTORE32((unsigned*)ctxslab + ((size_t)t * B_ + b) * 256 + tid, pk.u);
            }
            __syncthreads();
            if (tid == 0) ASTORE32(&ctxflag[b * SLOT], (unsigned)(t + 1));
            // ---- hw + ep partial (hw published during our attention) ----
            f16x8 ep = *(const f16x8*)&embP[((size_t)b * T_ + t) * G4 + 8 * tid];
            wait_n(hwflag, NG, (unsigned)(t + 1));
            float gp[8];
            {
                f16x8 hw = *(const f16x8*)&hwslab[((size_t)t * B_ + b) * G4 + 8 * tid];
#pragma unroll
                for (int i = 0; i < 8; ++i) gp[i] = (float)hw[i] + (float)ep[i];
            }
            // ---- cw (pass2), pointwise ----
            wait_n(cwflag, NG, (unsigned)(t + 1));
            {
                f16x8 cw = *(const f16x8*)&cwslab[((size_t)t * B_ + b) * G4 + 8 * tid];
                float gA[8];
#pragma unroll
                for (int i = 0; i < 8; ++i) gA[i] = gp[i] + (float)cw[i];
                float cn0 = sigm(gA[1]) * cs0 + sigm(gA[0]) * tanh_f(gA[2]);
                float cn1 = sigm(gA[5]) * cs1 + sigm(gA[4]) * tanh_f(gA[6]);
                float hn0 = sigm(gA[3]) * tanh_f(cn0);
                float hn1 = sigm(gA[7]) * tanh_f(cn1);
                cs0 = cn0; cs1 = cn1;
                union { f16 h[2]; unsigned u; } pk;
                pk.h[0] = (f16)hn0; pk.h[1] = (f16)hn1;
                S->hL[tid] = pk.u;
                ASTORE32((unsigned*)hslab + ((size_t)(t + 1) * B_ + b) * 256 + tid, pk.u);
            }
            __syncthreads();
            if (tid == 0)
                ASTORE32(&gateflag[b * SLOT], (unsigned)(t + 2));
        }
    } else if (bid < 64 + NG) {
        // ======== gemm block g: permuted cols [32g,32g+32) = hidden [8g,8g+8) ========
        int g = bid - 64;
        GemmSm* S = (GemmSm*)smraw;
        // pack own Whidp slice (k4 = 2g, 2g+1) via sc1, flag early
        {
#pragma unroll
            for (int s = 0; s < 2; ++s) {
                int k4 = 2 * g + s;
                f16 buf[4];
#pragma unroll
                for (int j = 0; j < 4; ++j)
                    buf[j] = (f16)W_hid[(size_t)(4 * k4 + j) * A_ + tid];
                union { f16 h[4]; ull u; } pk;
                *(f16x4*)pk.h = *(f16x4*)buf;
                ASTORE64((ull*)&Whidp[((size_t)k4 * 256 + tid) * 4], pk.u);
            }
        }
        __syncthreads();   // drains vmcnt: Whidp sc1 stores acked
        if (tid == 0) ASTORE32(&whidflag[g * SLOT], 1u);
        // stage both weight slices from raw f32 (inline transpose, XOR swizzle)
        for (int rowbase = 0; rowbase < 512; rowbase += 256) {
            int k = rowbase + tid;
            const float* wh = W_hh + (size_t)k * G4 + 8 * g;
            const float* wi = W_ih + (size_t)(E_ + k) * G4 + 8 * g;
            int ch = k >> 3, j = k & 7;
#pragma unroll
            for (int q = 0; q < 4; ++q) {
                float4 v0 = *(const float4*)(wh + q * 512);
                float4 v1 = *(const float4*)(wh + q * 512 + 4);
                float4 u0 = *(const float4*)(wi + q * 512);
                float4 u1 = *(const float4*)(wi + q * 512 + 4);
                float vv[8] = {v0.x,v0.y,v0.z,v0.w, v1.x,v1.y,v1.z,v1.w};
                float uu[8] = {u0.x,u0.y,u0.z,u0.w, u1.x,u1.y,u1.z,u1.w};
#pragma unroll
                for (int d = 0; d < 8; ++d) {
                    int r = d * 4 + q;
                    S->w[r][((ch ^ (r & 7)) << 3) + j]  = (f16)vv[d];
                    S->w2[r][((ch ^ (r & 7)) << 3) + j] = (f16)uu[d];
                }
            }
        }
        int wvv = tid >> 6, lane = tid & 63;
        int frow = lane & 15, q = lane >> 4, sw = frow & 7, rq = q * 4;
        int mb = (wvv >> 1) * 32, c16 = (wvv & 1) * 16;
        int bo = tid >> 2, cq = (tid & 3) * 8;
        __syncthreads();

        for (int t = 0; t < T_; ++t) {
            wait_n(gateflag, 64, (unsigned)(t + 1));
            // gather h(t)
            {
                const f16* hsrc = hslab + (size_t)t * B_ * H_;
#pragma unroll
                for (int i = 0; i < 16; ++i) {
                    int idx = i * 256 + tid;
                    int r = idx >> 6, ch = idx & 63;
                    *(f16x8*)&S->u.hs[r][(ch ^ (r & 7)) * 8] =
                        *(const f16x8*)&hsrc[(size_t)r * H_ + ch * 8];
                }
            }
            __syncthreads();
            // pass 1: h @ Whh-slice
            f32x4 a4[2];
            a4[0][0]=0.f; a4[0][1]=0.f; a4[0][2]=0.f; a4[0][3]=0.f;
            a4[1][0]=0.f; a4[1][1]=0.f; a4[1][2]=0.f; a4[1][3]=0.f;
#pragma unroll
            for (int kk = 0; kk < 16; ++kk) {
                int ch = ((kk * 4 + q) ^ sw) * 8;
                f16x8 bv = *(f16x8*)&S->w[c16 + frow][ch];
                f16x8 av0 = *(f16x8*)&S->u.hs[mb + frow][ch];
                f16x8 av1 = *(f16x8*)&S->u.hs[mb + 16 + frow][ch];
                a4[0] = __builtin_amdgcn_mfma_f32_16x16x32_f16(av0, bv, a4[0], 0, 0, 0);
                a4[1] = __builtin_amdgcn_mfma_f32_16x16x32_f16(av1, bv, a4[1], 0, 0, 0);
            }
            __syncthreads();   // hs reads done before hwT16 overwrite
#pragma unroll
            for (int mi = 0; mi < 2; ++mi)
#pragma unroll
                for (int r = 0; r < 4; ++r)
                    S->u.hwT16[mb + mi * 16 + rq + r][c16 + frow] = (f16)a4[mi][r];
            __syncthreads();
            // publish hw (pass-1 result) NOW — lands during gate's attention
            {
                f16* dst = hwslab + ((size_t)t * B_ + bo) * G4 + 32 * g + cq;
                union { f16 h[4]; ull u; } pk0, pk1;
                *(f16x4*)pk0.h = *(f16x4*)&S->u.hwT16[bo][cq];
                *(f16x4*)pk1.h = *(f16x4*)&S->u.hwT16[bo][cq + 4];
                ASTORE64(dst, pk0.u);
                ASTORE64(dst + 4, pk1.u);
            }
            __syncthreads();   // drains vmcnt: hw stores acked
            if (tid == 0) ASTORE32(&hwflag[g * SLOT], (unsigned)(t + 1));
            // pass 2: ctx @ Wih2-slice
            wait_n(ctxflag, 64, (unsigned)(t + 1));
            {
                const f16* csrc = ctxslab + (size_t)t * B_ * F_;
#pragma unroll
                for (int i = 0; i < 16; ++i) {
                    int idx = i * 256 + tid;
                    int r = idx >> 6, ch = idx & 63;
                    *(f16x8*)&S->u.hs[r][(ch ^ (r & 7)) * 8] =
                        *(const f16x8*)&csrc[(size_t)r * F_ + ch * 8];
                }
            }
            __syncthreads();
            f32x4 c4[2];
            c4[0][0]=0.f; c4[0][1]=0.f; c4[0][2]=0.f; c4[0][3]=0.f;
            c4[1][0]=0.f; c4[1][1]=0.f; c4[1][2]=0.f; c4[1][3]=0.f;
#pragma unroll
            for (int kk = 0; kk < 16; ++kk) {
                int ch = ((kk * 4 + q) ^ sw) * 8;
                f16x8 bv = *(f16x8*)&S->w2[c16 + frow][ch];
                f16x8 av0 = *(f16x8*)&S->u.hs[mb + frow][ch];
                f16x8 av1 = *(f16x8*)&S->u.hs[mb + 16 + frow][ch];
                c4[0] = __builtin_amdgcn_mfma_f32_16x16x32_f16(av0, bv, c4[0], 0, 0, 0);
                c4[1] = __builtin_amdgcn_mfma_f32_16x16x32_f16(av1, bv, c4[1], 0, 0, 0);
            }
            __syncthreads();   // hs reads done
#pragma unroll
            for (int mi = 0; mi < 2; ++mi)
#pragma unroll
                for (int r = 0; r < 4; ++r)
                    S->u.hwT16[mb + mi * 16 + rq + r][c16 + frow] = (f16)c4[mi][r];
            __syncthreads();
            {
                f16* dst = cwslab + ((size_t)t * B_ + bo) * G4 + 32 * g + cq;
                union { f16 h[4]; ull u; } pk0, pk1;
                *(f16x4*)pk0.h = *(f16x4*)&S->u.hwT16[bo][cq];
                *(f16x4*)pk1.h = *(f16x4*)&S->u.hwT16[bo][cq + 4];
                ASTORE64(dst, pk0.u);
                ASTORE64(dst + 4, pk1.u);
            }
            __syncthreads();   // drains vmcnt: cw stores acked
            if (tid == 0) ASTORE32(&cwflag[g * SLOT], (unsigned)(t + 1));
        }
    } else {
        // ======== logit block: W_out cols [nt*256, nt*256+256) ========
        int nt = bid - 64 - NG;
        int n0 = nt * 256;
        LogSm* S = (LogSm*)smraw;
        int wvv = tid >> 6, lane = tid & 63;
        int frow = lane & 15, q = lane >> 4, sw = frow & 7, rq = q * 4;

        // lazy transpose of own W_out slice (f32 -> f16 [col][k])
        {
            float (*ls)[33] = (float(*)[33])smraw;
            int rr = tid >> 3, cs = (tid & 7) * 4;
            int cr = tid >> 3, rs = (tid & 7) * 4;
            for (int c0 = 0; c0 < 256; c0 += 32)
                for (int k0 = 0; k0 < 512; k0 += 32) {
                    float4 v = *(const float4*)&W_out[(size_t)(k0 + rr) * V_ + n0 + c0 + cs];
                    __syncthreads();
                    ls[rr][cs] = v.x; ls[rr][cs + 1] = v.y; ls[rr][cs + 2] = v.z; ls[rr][cs + 3] = v.w;
                    __syncthreads();
                    f16x4 o = {(f16)ls[rs][cr], (f16)ls[rs + 1][cr],
                               (f16)ls[rs + 2][cr], (f16)ls[rs + 3][cr]};
                    *(f16x4*)&WoutT[(size_t)(n0 + c0 + cr) * 512 + k0 + rs] = o;
                }
            __syncthreads();
        }

        for (int tc = 0; tc < T_ / 2; ++tc) {
            wait_n_slow(gateflag, 64, (unsigned)(2 * tc + 3));
            {
                const f16* hsrc = hslab + (size_t)(2 * tc + 1) * B_ * H_;
#pragma unroll
                for (int i = 0; i < 32; ++i) {
                    int idx = i * 256 + tid;
                    int r = idx >> 6, ch = idx & 63;
                    *(f16x8*)&S->hs[r][(ch ^ (r & 7)) * 8] =
                        *(const f16x8*)&hsrc[(size_t)r * H_ + ch * 8];
                }
            }
            __syncthreads();
            f32x4 acc[8][4];
#pragma unroll
            for (int mi = 0; mi < 8; ++mi)
#pragma unroll
                for (int ni = 0; ni < 4; ++ni) { acc[mi][ni][0]=0.f; acc[mi][ni][1]=0.f; acc[mi][ni][2]=0.f; acc[mi][ni][3]=0.f; }
#pragma unroll 2
            for (int kk = 0; kk < 16; ++kk) {
                int ch = ((kk * 4 + q) ^ sw) * 8;
                f16x8 av[8], bv[4];
#pragma unroll
                for (int mi = 0; mi < 8; ++mi)
                    av[mi] = *(f16x8*)&S->hs[mi * 16 + frow][ch];
#pragma unroll
                for (int ni = 0; ni < 4; ++ni)
                    bv[ni] = *(const f16x8*)&WoutT[(size_t)(n0 + wvv * 64 + ni * 16 + frow) * 512 + kk * 32 + q * 8];
#pragma unroll
                for (int mi = 0; mi < 8; ++mi)
#pragma unroll
                    for (int ni = 0; ni < 4; ++ni)
                        acc[mi][ni] = __builtin_amdgcn_mfma_f32_16x16x32_f16(av[mi], bv[ni], acc[mi][ni], 0, 0, 0);
            }
#pragma unroll
            for (int ni = 0; ni < 4; ++ni) {
                int cc = n0 + wvv * 64 + ni * 16 + frow;
                float badd = b_out[cc];
#pragma unroll
                for (int mi = 0; mi < 8; ++mi)
#pragma unroll
                    for (int r = 0; r < 4; ++r) {
                        int rr = mi * 16 + rq + r;
                        int tt = 2 * tc + (rr >> 6), bb2 = rr & 63;
                        preds[((size_t)bb2 * T_ + tt) * V_ + cc] = acc[mi][ni][r] + badd;
                    }
            }
            __syncthreads();
        }
    }
}

// ================================================================ launch
extern "C" void kernel_launch(void* const* d_in, const int* in_sizes, int n_in,
                              void* d_out, int out_size, void* d_ws, size_t ws_size,
                              hipStream_t stream) {
    const float* image_feats = (const float*)d_in[0];
    const int*   caption     = (const int*)d_in[1];
    const float* embedding   = (const float*)d_in[2];
    const float* W_init_h    = (const float*)d_in[3];
    const float* b_init_h    = (const float*)d_in[4];
    const float* W_init_c    = (const float*)d_in[5];
    const float* b_init_c    = (const float*)d_in[6];
    const float* W_feat      = (const float*)d_in[7];
    const float* b_feat      = (const float*)d_in[8];
    const float* W_hid       = (const float*)d_in[9];
    const float* b_hid       = (const float*)d_in[10];
    const float* W_score     = (const float*)d_in[11];
    const float* b_score     = (const float*)d_in[12];
    const float* W_ih        = (const float*)d_in[13];
    const float* b_ih        = (const float*)d_in[14];
    const float* W_hh        = (const float*)d_in[15];
    const float* b_hh        = (const float*)d_in[16];
    const float* W_out       = (const float*)d_in[17];
    const float* b_out       = (const float*)d_in[18];

    float* preds = (float*)d_out;                                   // (B,T,V)
    float* out_alpha = preds + (size_t)B_ * T_ * V_;                // (B,T,L)

    size_t off = 0;
    char* base = (char*)d_ws;
    auto carve = [&](size_t bytes) {
        void* p = base + off;
        off += (bytes + 255) & ~(size_t)255;
        return p;
    };
    f16* embP       = (f16*)carve((size_t)B_ * T_ * G4 * 2);        // 8.4 MB
    f16* hslab      = (f16*)carve((size_t)(T_ + 1) * B_ * H_ * 2);  // 2.1 MB
    f16* ctxslab    = (f16*)carve((size_t)T_ * B_ * F_ * 2);        // 2.1 MB
    f16* hwslab     = (f16*)carve((size_t)T_ * B_ * G4 * 2);        // 8 MB
    f16* cwslab     = (f16*)carve((size_t)T_ * B_ * G4 * 2);        // 8 MB
    unsigned* flags = (unsigned*)carve(5 * 64 * SLOT * 4);
    f16* WoutT      = (f16*)carve((size_t)V_ * H_ * 2);             // 32.8 MB
    f16* Whidp      = (f16*)carve((size_t)H_ * A_ * 2);
    unsigned* gateflag = flags;
    unsigned* ctxflag  = flags + 64 * SLOT;
    unsigned* hwflag   = flags + 128 * SLOT;
    unsigned* cwflag   = flags + 192 * SLOT;
    unsigned* whidflag = flags + 256 * SLOT;
    (void)ws_size; (void)in_sizes; (void)n_in; (void)out_size;

    // 1) reset flags
    hipMemsetAsync(flags, 0, 5 * 64 * SLOT * 4, stream);
    // 2) embP GEMM (separate dispatch: plain stores + kernel-boundary visibility)
    hipLaunchKernelGGL(k_prep, dim3((B_ * T_ / 128) * (G4 / 128)), dim3(256), 0, stream,
                       caption, embedding, W_ih, b_ih, b_hh, embP);
    // 3) persistent recurrence + shadowed logits (253 blocks, co-resident)
    hipLaunchKernelGGL(k_steps, dim3(64 + NG + NLOG), dim3(256), 0, stream,
                       W_hh, W_ih, W_hid, Whidp, image_feats,
                       W_feat, b_feat, W_init_h, b_init_h, W_init_c, b_init_c,
                       b_hid, W_score, b_score, embP,
                       hslab, ctxslab, hwslab, cwslab,
                       W_out, WoutT, b_out, preds, out_alpha,
                       gateflag, ctxflag, hwflag, cwflag, whidflag);
}

// Round 17
// 618.225 us; speedup vs baseline: 1.3201x; 1.3201x over previous
//
#include <hip/hip_runtime.h>
#include <hip/hip_bf16.h>

typedef _Float16 f16;
typedef _Float16 f16x8 __attribute__((ext_vector_type(8)));
typedef _Float16 f16x4 __attribute__((ext_vector_type(4)));
typedef _Float16 f16x2 __attribute__((ext_vector_type(2)));
typedef float f32x4 __attribute__((ext_vector_type(4)));
typedef unsigned long long ull;

#define B_ 64
#define T_ 32
#define L_ 49
#define F_ 512
#define H_ 512
#define A_ 256
#define E_ 256
#define V_ 32000
#define G4 2048
#define NG 64       // recurrent-gemm blocks (8 hidden = 32 permuted cols, Whh+Wih2)
#define NLOG 125    // logit blocks (256 cols each), t-chunk = 2, lazy W_out transpose
#define SLOT 16

#define ALOAD32(p)     __hip_atomic_load((const unsigned*)(p), __ATOMIC_RELAXED, __HIP_MEMORY_SCOPE_AGENT)
#define ASTORE32(p, v) __hip_atomic_store((unsigned*)(p), (v), __ATOMIC_RELAXED, __HIP_MEMORY_SCOPE_AGENT)
#define ASTORE64(p, v) __hip_atomic_store((ull*)(p), (v), __ATOMIC_RELAXED, __HIP_MEMORY_SCOPE_AGENT)

#if defined(__has_builtin)
#if __has_builtin(__builtin_amdgcn_fdot2)
#define HAS_FDOT2 1
#endif
#endif

// ================================================================ fused prologue
// segments: embP GEMM (raw gather+transpose staging), Whidp pack, init, featproj
#define NB_EMBG 256
#define NB_Q    128
#define NB_INIT 64
#define NB_FP   196

struct Smem128 { f16 As[128][40]; f16 Bs[128][40]; };

__global__ __launch_bounds__(256) void k_prep(
    const float* __restrict__ image_feats, const int* __restrict__ caption,
    const float* __restrict__ embedding,
    const float* __restrict__ W_init_h, const float* __restrict__ b_init_h,
    const float* __restrict__ W_init_c, const float* __restrict__ b_init_c,
    const float* __restrict__ W_feat, const float* __restrict__ b_feat,
    const float* __restrict__ W_hid, const float* __restrict__ W_ih,
    const float* __restrict__ b_ih, const float* __restrict__ b_hh,
    f16* __restrict__ embP, f16* __restrict__ Whidp,
    f16* __restrict__ hslab, float* __restrict__ c_cur,
    float* __restrict__ featproj) {
    __shared__ __align__(16) char smem[32768];
    int bid = blockIdx.x, tid = threadIdx.x;
    int r = bid;
    if (r < NB_EMBG) {
        // embP = gather(embedding, caption) @ W_ih[:E,:] + b_ih + b_hh, gate-permuted f16
        Smem128* sm = (Smem128*)smem;
        int mtiles = B_ * T_ / 128;
        int m0 = (r % mtiles) * 128, n0 = (r / mtiles) * 128;
        int lane = tid & 63, wave = tid >> 6;
        int wr = (wave >> 1) * 64, wc = (wave & 1) * 64;
        int frow = lane & 15, fk = (lane >> 4) * 8;
        int ra = tid >> 2, ka = (tid & 3) * 8;
        int kb = tid >> 3, nb = (tid & 7) * 16;
        int tok0 = caption[m0 + ra], tok1 = caption[m0 + 64 + ra];
        f32x4 acc[4][4];
#pragma unroll
        for (int i = 0; i < 4; ++i)
#pragma unroll
            for (int j = 0; j < 4; ++j) { acc[i][j][0]=0.f; acc[i][j][1]=0.f; acc[i][j][2]=0.f; acc[i][j][3]=0.f; }
        for (int k0 = 0; k0 < E_; k0 += 32) {
            float4 e00 = *(const float4*)&embedding[(size_t)tok0 * E_ + k0 + ka];
            float4 e01 = *(const float4*)&embedding[(size_t)tok0 * E_ + k0 + ka + 4];
            float4 e10 = *(const float4*)&embedding[(size_t)tok1 * E_ + k0 + ka];
            float4 e11 = *(const float4*)&embedding[(size_t)tok1 * E_ + k0 + ka + 4];
            const float* wrow = W_ih + (size_t)(k0 + kb) * G4 + n0 + nb;
            float4 w0 = *(const float4*)wrow;
            float4 w1 = *(const float4*)(wrow + 4);
            float4 w2 = *(const float4*)(wrow + 8);
            float4 w3 = *(const float4*)(wrow + 12);
            __syncthreads();
            {
                f16x8 a0 = {(f16)e00.x,(f16)e00.y,(f16)e00.z,(f16)e00.w,
                            (f16)e01.x,(f16)e01.y,(f16)e01.z,(f16)e01.w};
                f16x8 a1 = {(f16)e10.x,(f16)e10.y,(f16)e10.z,(f16)e10.w,
                            (f16)e11.x,(f16)e11.y,(f16)e11.z,(f16)e11.w};
                *(f16x8*)&sm->As[ra][ka] = a0;
                *(f16x8*)&sm->As[64 + ra][ka] = a1;
                float wv[16] = {w0.x,w0.y,w0.z,w0.w, w1.x,w1.y,w1.z,w1.w,
                                w2.x,w2.y,w2.z,w2.w, w3.x,w3.y,w3.z,w3.w};
#pragma unroll
                for (int j = 0; j < 16; ++j) sm->Bs[nb + j][kb] = (f16)wv[j];
            }
            __syncthreads();
            f16x8 av[4], bv[4];
#pragma unroll
            for (int i = 0; i < 4; ++i) {
                av[i] = *(f16x8*)&sm->As[wr + i * 16 + frow][fk];
                bv[i] = *(f16x8*)&sm->Bs[wc + i * 16 + frow][fk];
            }
#pragma unroll
            for (int mi = 0; mi < 4; ++mi)
#pragma unroll
                for (int ni = 0; ni < 4; ++ni)
                    acc[mi][ni] = __builtin_amdgcn_mfma_f32_16x16x32_f16(av[mi], bv[ni], acc[mi][ni], 0, 0, 0);
        }
        int rq = (lane >> 4) * 4;
#pragma unroll
        for (int mi = 0; mi < 4; ++mi)
#pragma unroll
            for (int ni = 0; ni < 4; ++ni) {
                int cc = n0 + wc + ni * 16 + frow;
                float badd = b_ih[cc] + b_hh[cc];
#pragma unroll
                for (int rr2 = 0; rr2 < 4; ++rr2) {
                    int rr = m0 + wr + mi * 16 + rq + rr2;
                    embP[((size_t)rr * 512 + (cc & 511)) * 4 + (cc >> 9)] =
                        (f16)(acc[mi][ni][rr2] + badd);
                }
            }
        return;
    }
    r -= NB_EMBG;
    if (r < NB_Q) {
        int k4 = r;
        f16 buf[4];
#pragma unroll
        for (int j = 0; j < 4; ++j) buf[j] = (f16)W_hid[(size_t)(4 * k4 + j) * 256 + tid];
        *(f16x4*)&Whidp[((size_t)k4 * 256 + tid) * 4] = *(f16x4*)buf;
        return;
    }
    r -= NB_Q;
    if (r < NB_INIT) {
        float* mean = (float*)smem;
        int b = r;
        for (int f = tid; f < F_; f += 256) {
            float s = 0.f;
            for (int l = 0; l < L_; ++l) s += image_feats[((size_t)b * L_ + l) * F_ + f];
            mean[f] = s * (1.f / 49.f);
        }
        __syncthreads();
        for (int h = tid; h < H_; h += 256) {
            float a = b_init_h[h], c = b_init_c[h];
            for (int k = 0; k < F_; ++k) {
                float m = mean[k];
                a += m * W_init_h[k * H_ + h];
                c += m * W_init_c[k * H_ + h];
            }
            hslab[(size_t)b * H_ + h] = (f16)a;
            c_cur[b * H_ + h] = c;
        }
        return;
    }
    r -= NB_INIT;
    {
        float (*fs)[F_] = (float(*)[F_])smem;
        int r0 = r * 16;
        for (int i = tid; i < 16 * F_; i += 256)
            fs[i >> 9][i & 511] = image_feats[(size_t)r0 * F_ + i];
        __syncthreads();
        float acc[16];
#pragma unroll
        for (int q = 0; q < 16; ++q) acc[q] = 0.f;
        for (int k = 0; k < F_; ++k) {
            float w = W_feat[k * A_ + tid];
#pragma unroll
            for (int q = 0; q < 16; ++q) acc[q] += fs[q][k] * w;
        }
        float bb = b_feat[tid];
#pragma unroll
        for (int q = 0; q < 16; ++q) featproj[(size_t)(r0 + q) * A_ + tid] = acc[q] + bb;
    }
}

// ================================================================ persistent kernel
struct GateSm {
    float fp[L_][A_];        // featproj  (50 KB)
    unsigned fe[L_ * 256];   // feats as packed f16 pairs (50 KB)
    float ea[A_];
    float ws[A_];
    float sc[64];
    float alpha[64];
    unsigned hL[256];
};
struct GemmSm {
    f16 w[32][512];          // Whh slice, XOR-swizzled (32 KB)
    f16 w2[32][512];         // Wih2 slice (32 KB)
    union {
        f16 hs[64][512];     // h / ctx stage (64 KB, swizzled)
        f16 hwT16[64][40];
    } u;
};
struct LogSm { f16 hs[128][512]; };

__device__ __forceinline__ void wait_n(const unsigned* flags, int n, unsigned target) {
    int tid = threadIdx.x;
    if (tid < n) {
        const unsigned* p = flags + tid * SLOT;
        while (ALOAD32(p) < target) __builtin_amdgcn_s_sleep(1);
    }
    asm volatile("" ::: "memory");
    __syncthreads();
}
__device__ __forceinline__ void wait_n_slow(const unsigned* flags, int n, unsigned target) {
    int tid = threadIdx.x;
    if (tid < n) {
        const unsigned* p = flags + tid * SLOT;
        while (ALOAD32(p) < target) __builtin_amdgcn_s_sleep(8);
    }
    asm volatile("" ::: "memory");
    __syncthreads();
}

__device__ __forceinline__ float sigm(float x) { return 1.f / (1.f + __expf(-x)); }
__device__ __forceinline__ float tanh_f(float x) { return 1.f - 2.f / (1.f + __expf(2.f * x)); }

__global__ __launch_bounds__(256, 1) void k_steps(
    const float* __restrict__ W_hh, const float* __restrict__ W_ih,
    const f16* __restrict__ Whidp,
    const float* __restrict__ featproj, const float* __restrict__ image_feats,
    const float* __restrict__ b_hid,
    const float* __restrict__ W_score, const float* __restrict__ b_score,
    const f16* __restrict__ embP, const float* __restrict__ c_cur,
    f16* __restrict__ hslab, f16* __restrict__ ctxslab, f16* __restrict__ hwcslab,
    const float* __restrict__ W_out, f16* __restrict__ WoutT,
    const float* __restrict__ b_out,
    float* __restrict__ preds, float* __restrict__ out_alpha,
    unsigned* __restrict__ gateflag, unsigned* __restrict__ ctxflag,
    unsigned* __restrict__ gemmflag) {
    __shared__ __align__(16) char smraw[sizeof(LogSm)];
    int bid = blockIdx.x, tid = threadIdx.x;

    if (bid < 64) {
        // ======== gate block for batch b ========
        int b = bid;
        GateSm* S = (GateSm*)smraw;
        for (int i = tid; i < L_ * A_; i += 256)
            ((float*)S->fp)[i] = featproj[(size_t)b * L_ * A_ + i];
        {   // stage feats[b] raw f32 -> packed f16 pairs
            const float2* src = (const float2*)(image_feats + (size_t)b * L_ * F_);
            for (int i = tid; i < L_ * 256; i += 256) {
                float2 v = src[i];
                union { f16 h[2]; unsigned u; } pk;
                pk.h[0] = (f16)v.x; pk.h[1] = (f16)v.y;
                S->fe[i] = pk.u;
            }
        }
        S->ws[tid] = W_score[tid];
        float bhid_r = b_hid[tid];
        float bsc = b_score[0];
        S->hL[tid] = ((const unsigned*)hslab)[(size_t)b * 256 + tid];
        float cs0 = c_cur[b * H_ + 2 * tid], cs1 = c_cur[b * H_ + 2 * tid + 1];
        const f16x4* wp4 = (const f16x4*)Whidp;
        int wv = tid >> 6, ln = tid & 63;
        __syncthreads();

        for (int t = 0; t < T_; ++t) {
            // ---- ea = h @ W_hid + b_hid (k-quad 8B loads, 2x fdot2) ----
            {
                float acc = bhid_r;
#pragma unroll 16
                for (int k4 = 0; k4 < 128; ++k4) {
                    union { f16x4 v; f16x2 p[2]; } w;
                    w.v = wp4[(size_t)k4 * 256 + tid];
                    union { unsigned u; f16x2 v; } h0, h1;
                    h0.u = S->hL[2 * k4];
                    h1.u = S->hL[2 * k4 + 1];
#ifdef HAS_FDOT2
                    acc = __builtin_amdgcn_fdot2(w.p[0], h0.v, acc, false);
                    acc = __builtin_amdgcn_fdot2(w.p[1], h1.v, acc, false);
#else
                    acc += (float)w.p[0].x * (float)h0.v.x + (float)w.p[0].y * (float)h0.v.y;
                    acc += (float)w.p[1].x * (float)h1.v.x + (float)w.p[1].y * (float)h1.v.y;
#endif
                }
                S->ea[tid] = acc;
            }
            __syncthreads();
            // ---- scores ----
            for (int l = wv; l < L_; l += 4) {
                float p = 0.f;
#pragma unroll
                for (int q = 0; q < 4; ++q) {
                    int j = ln + q * 64;
                    p += tanh_f(S->fp[l][j] + S->ea[j]) * S->ws[j];
                }
#pragma unroll
                for (int off = 32; off > 0; off >>= 1) p += __shfl_xor(p, off);
                if (ln == 0) S->sc[l] = p;
            }
            __syncthreads();
            // ---- softmax (wave 0) ----
            if (tid < 64) {
                float v = (tid < L_) ? S->sc[tid] + bsc : -3.4e38f;
                float m = v;
#pragma unroll
                for (int off = 32; off > 0; off >>= 1) m = fmaxf(m, __shfl_xor(m, off));
                float e = (tid < L_) ? __expf(v - m) : 0.f;
                float s = e;
#pragma unroll
                for (int off = 32; off > 0; off >>= 1) s += __shfl_xor(s, off);
                if (tid < L_) {
                    float al = e / s;
                    S->alpha[tid] = al;
                    out_alpha[((size_t)b * T_ + t) * L_ + tid] = al;
                }
            }
            __syncthreads();
            // ---- ep prefetch (independent; hides under ctx reduction) ----
            f16x8 ep = *(const f16x8*)&embP[((size_t)b * T_ + t) * G4 + 8 * tid];
            // ---- ctx = sum_l alpha_l * feats[b,l,:]; publish ----
            {
                float c0 = 0.f, c1 = 0.f;
#pragma unroll 7
                for (int l = 0; l < L_; ++l) {
                    float a = S->alpha[l];
                    union { unsigned u; f16x2 v; } fv;
                    fv.u = S->fe[l * 256 + tid];
                    c0 += a * (float)fv.v.x;
                    c1 += a * (float)fv.v.y;
                }
                union { f16 h[2]; unsigned u; } pk;
                pk.h[0] = (f16)c0; pk.h[1] = (f16)c1;
                ASTORE32((unsigned*)ctxslab + ((size_t)t * B_ + b) * 256 + tid, pk.u);
            }
            __syncthreads();
            if (tid == 0) ASTORE32(&ctxflag[b * SLOT], (unsigned)(t + 1));
            // ---- wait combined recurrent matmul, pointwise ----
            wait_n(gemmflag, NG, (unsigned)(t + 1));
            {
                f16x8 hw = *(const f16x8*)&hwcslab[((size_t)t * B_ + b) * G4 + 8 * tid];
                float gA[8];
#pragma unroll
                for (int i = 0; i < 8; ++i) gA[i] = (float)hw[i] + (float)ep[i];
                float cn0 = sigm(gA[1]) * cs0 + sigm(gA[0]) * tanh_f(gA[2]);
                float cn1 = sigm(gA[5]) * cs1 + sigm(gA[4]) * tanh_f(gA[6]);
                float hn0 = sigm(gA[3]) * tanh_f(cn0);
                float hn1 = sigm(gA[7]) * tanh_f(cn1);
                cs0 = cn0; cs1 = cn1;
                union { f16 h[2]; unsigned u; } pk;
                pk.h[0] = (f16)hn0; pk.h[1] = (f16)hn1;
                S->hL[tid] = pk.u;
                ASTORE32((unsigned*)hslab + ((size_t)(t + 1) * B_ + b) * 256 + tid, pk.u);
            }
            __syncthreads();
            if (tid == 0)
                ASTORE32(&gateflag[b * SLOT], (unsigned)(t + 2));
        }
    } else if (bid < 64 + NG) {
        // ======== gemm block g: permuted cols [32g,32g+32) = hidden [8g,8g+8) ========
        int g = bid - 64;
        GemmSm* S = (GemmSm*)smraw;
        // one-time raw-f32 staging with inline transpose:
        // permuted local col r: actual col = (r&3)*512 + 8g + (r>>2)
        for (int rowbase = 0; rowbase < 512; rowbase += 256) {
            int k = rowbase + tid;
            const float* wh = W_hh + (size_t)k * G4 + 8 * g;
            const float* wi = W_ih + (size_t)(E_ + k) * G4 + 8 * g;
            int ch = k >> 3, j = k & 7;
#pragma unroll
            for (int q = 0; q < 4; ++q) {
                float4 v0 = *(const float4*)(wh + q * 512);
                float4 v1 = *(const float4*)(wh + q * 512 + 4);
                float4 u0 = *(const float4*)(wi + q * 512);
                float4 u1 = *(const float4*)(wi + q * 512 + 4);
                float vv[8] = {v0.x,v0.y,v0.z,v0.w, v1.x,v1.y,v1.z,v1.w};
                float uu[8] = {u0.x,u0.y,u0.z,u0.w, u1.x,u1.y,u1.z,u1.w};
#pragma unroll
                for (int d = 0; d < 8; ++d) {
                    int r = d * 4 + q;
                    S->w[r][((ch ^ (r & 7)) << 3) + j]  = (f16)vv[d];
                    S->w2[r][((ch ^ (r & 7)) << 3) + j] = (f16)uu[d];
                }
            }
        }
        int wvv = tid >> 6, lane = tid & 63;
        int frow = lane & 15, q = lane >> 4, sw = frow & 7, rq = q * 4;
        int mb = (wvv >> 1) * 32, c16 = (wvv & 1) * 16;
        int bo = tid >> 2, cq = (tid & 3) * 8;
        __syncthreads();

        for (int t = 0; t < T_; ++t) {
            if (t) wait_n(gateflag, 64, (unsigned)(t + 1));
            {
                const f16* hsrc = hslab + (size_t)t * B_ * H_;
#pragma unroll
                for (int i = 0; i < 16; ++i) {
                    int idx = i * 256 + tid;
                    int r = idx >> 6, ch = idx & 63;
                    *(f16x8*)&S->u.hs[r][(ch ^ (r & 7)) * 8] =
                        *(const f16x8*)&hsrc[(size_t)r * H_ + ch * 8];
                }
            }
            __syncthreads();
            f32x4 a4[2];
            a4[0][0]=0.f; a4[0][1]=0.f; a4[0][2]=0.f; a4[0][3]=0.f;
            a4[1][0]=0.f; a4[1][1]=0.f; a4[1][2]=0.f; a4[1][3]=0.f;
#pragma unroll
            for (int kk = 0; kk < 16; ++kk) {
                int ch = ((kk * 4 + q) ^ sw) * 8;
                f16x8 bv = *(f16x8*)&S->w[c16 + frow][ch];
                f16x8 av0 = *(f16x8*)&S->u.hs[mb + frow][ch];
                f16x8 av1 = *(f16x8*)&S->u.hs[mb + 16 + frow][ch];
                a4[0] = __builtin_amdgcn_mfma_f32_16x16x32_f16(av0, bv, a4[0], 0, 0, 0);
                a4[1] = __builtin_amdgcn_mfma_f32_16x16x32_f16(av1, bv, a4[1], 0, 0, 0);
            }
            wait_n(ctxflag, 64, (unsigned)(t + 1));
            {
                const f16* csrc = ctxslab + (size_t)t * B_ * F_;
#pragma unroll
                for (int i = 0; i < 16; ++i) {
                    int idx = i * 256 + tid;
                    int r = idx >> 6, ch = idx & 63;
                    *(f16x8*)&S->u.hs[r][(ch ^ (r & 7)) * 8] =
                        *(const f16x8*)&csrc[(size_t)r * F_ + ch * 8];
                }
            }
            __syncthreads();
#pragma unroll
            for (int kk = 0; kk < 16; ++kk) {
                int ch = ((kk * 4 + q) ^ sw) * 8;
                f16x8 bv = *(f16x8*)&S->w2[c16 + frow][ch];
                f16x8 av0 = *(f16x8*)&S->u.hs[mb + frow][ch];
                f16x8 av1 = *(f16x8*)&S->u.hs[mb + 16 + frow][ch];
                a4[0] = __builtin_amdgcn_mfma_f32_16x16x32_f16(av0, bv, a4[0], 0, 0, 0);
                a4[1] = __builtin_amdgcn_mfma_f32_16x16x32_f16(av1, bv, a4[1], 0, 0, 0);
            }
            __syncthreads();
#pragma unroll
            for (int mi = 0; mi < 2; ++mi)
#pragma unroll
                for (int r = 0; r < 4; ++r)
                    S->u.hwT16[mb + mi * 16 + rq + r][c16 + frow] = (f16)a4[mi][r];
            __syncthreads();
            {
                f16* dst = hwcslab + ((size_t)t * B_ + bo) * G4 + 32 * g + cq;
                union { f16 h[4]; ull u; } pk0, pk1;
                *(f16x4*)pk0.h = *(f16x4*)&S->u.hwT16[bo][cq];
                *(f16x4*)pk1.h = *(f16x4*)&S->u.hwT16[bo][cq + 4];
                ASTORE64(dst, pk0.u);
                ASTORE64(dst + 4, pk1.u);
            }
            __syncthreads();
            if (tid == 0)
                ASTORE32(&gemmflag[g * SLOT], (unsigned)(t + 1));
        }
    } else {
        // ======== logit block: W_out cols [nt*256, nt*256+256) ========
        int nt = bid - 64 - NG;
        int n0 = nt * 256;
        LogSm* S = (LogSm*)smraw;
        int wvv = tid >> 6, lane = tid & 63;
        int frow = lane & 15, q = lane >> 4, sw = frow & 7, rq = q * 4;

        // ---- lazy transpose of own W_out slice (f32 -> f16 [col][k]) ----
        {
            float (*ls)[33] = (float(*)[33])smraw;
            int rr = tid >> 3, cs = (tid & 7) * 4;
            int cr = tid >> 3, rs = (tid & 7) * 4;
            for (int c0 = 0; c0 < 256; c0 += 32)
                for (int k0 = 0; k0 < 512; k0 += 32) {
                    float4 v = *(const float4*)&W_out[(size_t)(k0 + rr) * V_ + n0 + c0 + cs];
                    __syncthreads();
                    ls[rr][cs] = v.x; ls[rr][cs + 1] = v.y; ls[rr][cs + 2] = v.z; ls[rr][cs + 3] = v.w;
                    __syncthreads();
                    f16x4 o = {(f16)ls[rs][cr], (f16)ls[rs + 1][cr],
                               (f16)ls[rs + 2][cr], (f16)ls[rs + 3][cr]};
                    *(f16x4*)&WoutT[(size_t)(n0 + c0 + cr) * 512 + k0 + rs] = o;
                }
            __syncthreads();
        }

        for (int tc = 0; tc < T_ / 2; ++tc) {
            wait_n_slow(gateflag, 64, (unsigned)(2 * tc + 3));
            {
                const f16* hsrc = hslab + (size_t)(2 * tc + 1) * B_ * H_;
#pragma unroll
                for (int i = 0; i < 32; ++i) {
                    int idx = i * 256 + tid;
                    int r = idx >> 6, ch = idx & 63;
                    *(f16x8*)&S->hs[r][(ch ^ (r & 7)) * 8] =
                        *(const f16x8*)&hsrc[(size_t)r * H_ + ch * 8];
                }
            }
            __syncthreads();
            f32x4 acc[8][4];
#pragma unroll
            for (int mi = 0; mi < 8; ++mi)
#pragma unroll
                for (int ni = 0; ni < 4; ++ni) { acc[mi][ni][0]=0.f; acc[mi][ni][1]=0.f; acc[mi][ni][2]=0.f; acc[mi][ni][3]=0.f; }
#pragma unroll 2
            for (int kk = 0; kk < 16; ++kk) {
                int ch = ((kk * 4 + q) ^ sw) * 8;
                f16x8 av[8], bv[4];
#pragma unroll
                for (int mi = 0; mi < 8; ++mi)
                    av[mi] = *(f16x8*)&S->hs[mi * 16 + frow][ch];
#pragma unroll
                for (int ni = 0; ni < 4; ++ni)
                    bv[ni] = *(const f16x8*)&WoutT[(size_t)(n0 + wvv * 64 + ni * 16 + frow) * 512 + kk * 32 + q * 8];
#pragma unroll
                for (int mi = 0; mi < 8; ++mi)
#pragma unroll
                    for (int ni = 0; ni < 4; ++ni)
                        acc[mi][ni] = __builtin_amdgcn_mfma_f32_16x16x32_f16(av[mi], bv[ni], acc[mi][ni], 0, 0, 0);
            }
#pragma unroll
            for (int ni = 0; ni < 4; ++ni) {
                int cc = n0 + wvv * 64 + ni * 16 + frow;
                float badd = b_out[cc];
#pragma unroll
                for (int mi = 0; mi < 8; ++mi)
#pragma unroll
                    for (int r = 0; r < 4; ++r) {
                        int rr = mi * 16 + rq + r;
                        int tt = 2 * tc + (rr >> 6), bb2 = rr & 63;
                        preds[((size_t)bb2 * T_ + tt) * V_ + cc] = acc[mi][ni][r] + badd;
                    }
            }
            __syncthreads();
        }
    }
}

// ================================================================ launch
extern "C" void kernel_launch(void* const* d_in, const int* in_sizes, int n_in,
                              void* d_out, int out_size, void* d_ws, size_t ws_size,
                              hipStream_t stream) {
    const float* image_feats = (const float*)d_in[0];
    const int*   caption     = (const int*)d_in[1];
    const float* embedding   = (const float*)d_in[2];
    const float* W_init_h    = (const float*)d_in[3];
    const float* b_init_h    = (const float*)d_in[4];
    const float* W_init_c    = (const float*)d_in[5];
    const float* b_init_c    = (const float*)d_in[6];
    const float* W_feat      = (const float*)d_in[7];
    const float* b_feat      = (const float*)d_in[8];
    const float* W_hid       = (const float*)d_in[9];
    const float* b_hid       = (const float*)d_in[10];
    const float* W_score     = (const float*)d_in[11];
    const float* b_score     = (const float*)d_in[12];
    const float* W_ih        = (const float*)d_in[13];
    const float* b_ih        = (const float*)d_in[14];
    const float* W_hh        = (const float*)d_in[15];
    const float* b_hh        = (const float*)d_in[16];
    const float* W_out       = (const float*)d_in[17];
    const float* b_out       = (const float*)d_in[18];

    float* preds = (float*)d_out;                                   // (B,T,V)
    float* out_alpha = preds + (size_t)B_ * T_ * V_;                // (B,T,L)

    size_t off = 0;
    char* base = (char*)d_ws;
    auto carve = [&](size_t bytes) {
        void* p = base + off;
        off += (bytes + 255) & ~(size_t)255;
        return p;
    };
    f16* embP       = (f16*)carve((size_t)B_ * T_ * G4 * 2);        // 8.4 MB
    float* featproj = (float*)carve((size_t)B_ * L_ * A_ * 4);      // 3.2 MB
    float* c_cur    = (float*)carve((size_t)B_ * H_ * 4);
    f16* hslab      = (f16*)carve((size_t)(T_ + 1) * B_ * H_ * 2);  // 2.1 MB
    f16* ctxslab    = (f16*)carve((size_t)T_ * B_ * F_ * 2);        // 2.1 MB
    f16* hwcslab    = (f16*)carve((size_t)T_ * B_ * G4 * 2);        // 8 MB
    unsigned* flags = (unsigned*)carve((64 + 64 + NG) * SLOT * 4);
    f16* WoutT      = (f16*)carve((size_t)V_ * H_ * 2);             // 32.8 MB
    f16* Whidp      = (f16*)carve((size_t)H_ * A_ * 2);
    unsigned* gateflag = flags;
    unsigned* ctxflag  = flags + 64 * SLOT;
    unsigned* gemmflag = flags + 128 * SLOT;
    (void)ws_size; (void)in_sizes; (void)n_in; (void)out_size;

    // 1) reset flags
    hipMemsetAsync(flags, 0, (64 + 64 + NG) * SLOT * 4, stream);
    // 2) fused prologue: embP GEMM (raw gather/transpose) + Whidp + init + featproj
    hipLaunchKernelGGL(k_prep, dim3(NB_EMBG + NB_Q + NB_INIT + NB_FP), dim3(256), 0, stream,
                       image_feats, caption, embedding,
                       W_init_h, b_init_h, W_init_c, b_init_c,
                       W_feat, b_feat, W_hid, W_ih, b_ih, b_hh,
                       embP, Whidp, hslab, c_cur, featproj);
    // 3) persistent recurrence + shadowed logits (253 blocks, co-resident)
    hipLaunchKernelGGL(k_steps, dim3(64 + NG + NLOG), dim3(256), 0, stream,
                       W_hh, W_ih, Whidp, featproj, image_feats, b_hid,
                       W_score, b_score, embP, c_cur,
                       hslab, ctxslab, hwcslab,
                       W_out, WoutT, b_out, preds, out_alpha,
                       gateflag, ctxflag, gemmflag);
}

// Round 20
// 617.561 us; speedup vs baseline: 1.3215x; 1.0011x over previous
//
#include <hip/hip_runtime.h>
#include <hip/hip_bf16.h>

typedef _Float16 f16;
typedef _Float16 f16x8 __attribute__((ext_vector_type(8)));
typedef _Float16 f16x4 __attribute__((ext_vector_type(4)));
typedef _Float16 f16x2 __attribute__((ext_vector_type(2)));
typedef float f32x4 __attribute__((ext_vector_type(4)));
typedef unsigned long long ull;

#define B_ 64
#define T_ 32
#define L_ 49
#define F_ 512
#define H_ 512
#define A_ 256
#define E_ 256
#define V_ 32000
#define G4 2048
#define NG 64       // recurrent-gemm blocks (8 hidden = 32 permuted cols, Whh+Wih2)
#define NLOG 125    // logit blocks (256 cols each), t-chunk = 2, lazy W_out transpose
#define SLOT 16

#define ALOAD32(p)     __hip_atomic_load((const unsigned*)(p), __ATOMIC_RELAXED, __HIP_MEMORY_SCOPE_AGENT)
#define ASTORE32(p, v) __hip_atomic_store((unsigned*)(p), (v), __ATOMIC_RELAXED, __HIP_MEMORY_SCOPE_AGENT)
#define ASTORE64(p, v) __hip_atomic_store((ull*)(p), (v), __ATOMIC_RELAXED, __HIP_MEMORY_SCOPE_AGENT)

#if defined(__has_builtin)
#if __has_builtin(__builtin_amdgcn_fdot2)
#define HAS_FDOT2 1
#endif
#endif

// ================================================================ fused prologue
// segments: embP GEMM (raw gather+transpose staging), Whidp pack, init, featproj
#define NB_EMBG 256
#define NB_Q    128
#define NB_INIT 64
#define NB_FP   196

struct Smem128 { f16 As[128][40]; f16 Bs[128][40]; };

__global__ __launch_bounds__(256) void k_prep(
    const float* __restrict__ image_feats, const int* __restrict__ caption,
    const float* __restrict__ embedding,
    const float* __restrict__ W_init_h, const float* __restrict__ b_init_h,
    const float* __restrict__ W_init_c, const float* __restrict__ b_init_c,
    const float* __restrict__ W_feat, const float* __restrict__ b_feat,
    const float* __restrict__ W_hid, const float* __restrict__ W_ih,
    const float* __restrict__ b_ih, const float* __restrict__ b_hh,
    f16* __restrict__ embP, f16* __restrict__ Whidp,
    f16* __restrict__ hslab, float* __restrict__ c_cur,
    float* __restrict__ featproj) {
    __shared__ __align__(16) char smem[32768];
    int bid = blockIdx.x, tid = threadIdx.x;
    int r = bid;
    if (r < NB_EMBG) {
        // embP = gather(embedding, caption) @ W_ih[:E,:] + b_ih + b_hh, gate-permuted f16
        Smem128* sm = (Smem128*)smem;
        int mtiles = B_ * T_ / 128;
        int m0 = (r % mtiles) * 128, n0 = (r / mtiles) * 128;
        int lane = tid & 63, wave = tid >> 6;
        int wr = (wave >> 1) * 64, wc = (wave & 1) * 64;
        int frow = lane & 15, fk = (lane >> 4) * 8;
        int ra = tid >> 2, ka = (tid & 3) * 8;
        int kb = tid >> 3, nb = (tid & 7) * 16;
        int tok0 = caption[m0 + ra], tok1 = caption[m0 + 64 + ra];
        f32x4 acc[4][4];
#pragma unroll
        for (int i = 0; i < 4; ++i)
#pragma unroll
            for (int j = 0; j < 4; ++j) { acc[i][j][0]=0.f; acc[i][j][1]=0.f; acc[i][j][2]=0.f; acc[i][j][3]=0.f; }
        for (int k0 = 0; k0 < E_; k0 += 32) {
            float4 e00 = *(const float4*)&embedding[(size_t)tok0 * E_ + k0 + ka];
            float4 e01 = *(const float4*)&embedding[(size_t)tok0 * E_ + k0 + ka + 4];
            float4 e10 = *(const float4*)&embedding[(size_t)tok1 * E_ + k0 + ka];
            float4 e11 = *(const float4*)&embedding[(size_t)tok1 * E_ + k0 + ka + 4];
            const float* wrow = W_ih + (size_t)(k0 + kb) * G4 + n0 + nb;
            float4 w0 = *(const float4*)wrow;
            float4 w1 = *(const float4*)(wrow + 4);
            float4 w2 = *(const float4*)(wrow + 8);
            float4 w3 = *(const float4*)(wrow + 12);
            __syncthreads();
            {
                f16x8 a0 = {(f16)e00.x,(f16)e00.y,(f16)e00.z,(f16)e00.w,
                            (f16)e01.x,(f16)e01.y,(f16)e01.z,(f16)e01.w};
                f16x8 a1 = {(f16)e10.x,(f16)e10.y,(f16)e10.z,(f16)e10.w,
                            (f16)e11.x,(f16)e11.y,(f16)e11.z,(f16)e11.w};
                *(f16x8*)&sm->As[ra][ka] = a0;
                *(f16x8*)&sm->As[64 + ra][ka] = a1;
                float wv[16] = {w0.x,w0.y,w0.z,w0.w, w1.x,w1.y,w1.z,w1.w,
                                w2.x,w2.y,w2.z,w2.w, w3.x,w3.y,w3.z,w3.w};
#pragma unroll
                for (int j = 0; j < 16; ++j) sm->Bs[nb + j][kb] = (f16)wv[j];
            }
            __syncthreads();
            f16x8 av[4], bv[4];
#pragma unroll
            for (int i = 0; i < 4; ++i) {
                av[i] = *(f16x8*)&sm->As[wr + i * 16 + frow][fk];
                bv[i] = *(f16x8*)&sm->Bs[wc + i * 16 + frow][fk];
            }
#pragma unroll
            for (int mi = 0; mi < 4; ++mi)
#pragma unroll
                for (int ni = 0; ni < 4; ++ni)
                    acc[mi][ni] = __builtin_amdgcn_mfma_f32_16x16x32_f16(av[mi], bv[ni], acc[mi][ni], 0, 0, 0);
        }
        int rq = (lane >> 4) * 4;
#pragma unroll
        for (int mi = 0; mi < 4; ++mi)
#pragma unroll
            for (int ni = 0; ni < 4; ++ni) {
                int cc = n0 + wc + ni * 16 + frow;
                float badd = b_ih[cc] + b_hh[cc];
#pragma unroll
                for (int rr2 = 0; rr2 < 4; ++rr2) {
                    int rr = m0 + wr + mi * 16 + rq + rr2;
                    embP[((size_t)rr * 512 + (cc & 511)) * 4 + (cc >> 9)] =
                        (f16)(acc[mi][ni][rr2] + badd);
                }
            }
        return;
    }
    r -= NB_EMBG;
    if (r < NB_Q) {
        int k4 = r;
        f16 buf[4];
#pragma unroll
        for (int j = 0; j < 4; ++j) buf[j] = (f16)W_hid[(size_t)(4 * k4 + j) * 256 + tid];
        *(f16x4*)&Whidp[((size_t)k4 * 256 + tid) * 4] = *(f16x4*)buf;
        return;
    }
    r -= NB_Q;
    if (r < NB_INIT) {
        float* mean = (float*)smem;
        int b = r;
        for (int f = tid; f < F_; f += 256) {
            float s = 0.f;
            for (int l = 0; l < L_; ++l) s += image_feats[((size_t)b * L_ + l) * F_ + f];
            mean[f] = s * (1.f / 49.f);
        }
        __syncthreads();
        for (int h = tid; h < H_; h += 256) {
            float a = b_init_h[h], c = b_init_c[h];
            for (int k = 0; k < F_; ++k) {
                float m = mean[k];
                a += m * W_init_h[k * H_ + h];
                c += m * W_init_c[k * H_ + h];
            }
            hslab[(size_t)b * H_ + h] = (f16)a;
            c_cur[b * H_ + h] = c;
        }
        return;
    }
    r -= NB_INIT;
    {
        float (*fs)[F_] = (float(*)[F_])smem;
        int r0 = r * 16;
        for (int i = tid; i < 16 * F_; i += 256)
            fs[i >> 9][i & 511] = image_feats[(size_t)r0 * F_ + i];
        __syncthreads();
        float acc[16];
#pragma unroll
        for (int q = 0; q < 16; ++q) acc[q] = 0.f;
        for (int k = 0; k < F_; ++k) {
            float w = W_feat[k * A_ + tid];
#pragma unroll
            for (int q = 0; q < 16; ++q) acc[q] += fs[q][k] * w;
        }
        float bb = b_feat[tid];
#pragma unroll
        for (int q = 0; q < 16; ++q) featproj[(size_t)(r0 + q) * A_ + tid] = acc[q] + bb;
    }
}

// ================================================================ persistent kernel
struct GateSm {
    float fp[L_][A_];        // featproj  (50 KB)
    unsigned fe[L_ * 256];   // feats as packed f16 pairs (50 KB)
    float ea[A_];
    float ws[A_];
    float sc[64];
    float alpha[64];
    unsigned hL[256];
};
struct GemmSm {
    f16 w[32][512];          // Whh slice, XOR-swizzled (32 KB)
    f16 w2[32][512];         // Wih2 slice (32 KB)
    union {
        f16 hs[64][512];     // h / ctx stage (64 KB, swizzled)
        f16 hwT16[64][40];
    } u;
};
struct LogSm { f16 hs[128][512]; };

__device__ __forceinline__ void wait_n(const unsigned* flags, int n, unsigned target) {
    int tid = threadIdx.x;
    if (tid < n) {
        const unsigned* p = flags + tid * SLOT;
        while (ALOAD32(p) < target) __builtin_amdgcn_s_sleep(1);
    }
    asm volatile("" ::: "memory");
    __syncthreads();
}
__device__ __forceinline__ void wait_n_slow(const unsigned* flags, int n, unsigned target) {
    int tid = threadIdx.x;
    if (tid < n) {
        const unsigned* p = flags + tid * SLOT;
        while (ALOAD32(p) < target) __builtin_amdgcn_s_sleep(8);
    }
    asm volatile("" ::: "memory");
    __syncthreads();
}

__device__ __forceinline__ float sigm(float x) { return 1.f / (1.f + __expf(-x)); }
__device__ __forceinline__ float tanh_f(float x) { return 1.f - 2.f / (1.f + __expf(2.f * x)); }

__global__ __launch_bounds__(256, 1) void k_steps(
    const float* __restrict__ W_hh, const float* __restrict__ W_ih,
    const f16* __restrict__ Whidp,
    const float* __restrict__ featproj, const float* __restrict__ image_feats,
    const float* __restrict__ b_hid,
    const float* __restrict__ W_score, const float* __restrict__ b_score,
    const f16* __restrict__ embP, const float* __restrict__ c_cur,
    f16* __restrict__ hslab, f16* __restrict__ ctxslab, f16* __restrict__ hwcslab,
    const float* __restrict__ W_out, f16* __restrict__ WoutT,
    const float* __restrict__ b_out,
    float* __restrict__ preds, float* __restrict__ out_alpha,
    unsigned* __restrict__ gateflag, unsigned* __restrict__ ctxflag,
    unsigned* __restrict__ gemmflag) {
    __shared__ __align__(16) char smraw[sizeof(LogSm)];
    int bid = blockIdx.x, tid = threadIdx.x;

    if (bid < 64) {
        // ======== gate block for batch b ========
        int b = bid;
        GateSm* S = (GateSm*)smraw;
        for (int i = tid; i < L_ * A_; i += 256)
            ((float*)S->fp)[i] = featproj[(size_t)b * L_ * A_ + i];
        {   // stage feats[b] raw f32 -> packed f16 pairs
            const float2* src = (const float2*)(image_feats + (size_t)b * L_ * F_);
            for (int i = tid; i < L_ * 256; i += 256) {
                float2 v = src[i];
                union { f16 h[2]; unsigned u; } pk;
                pk.h[0] = (f16)v.x; pk.h[1] = (f16)v.y;
                S->fe[i] = pk.u;
            }
        }
        S->ws[tid] = W_score[tid];
        float bhid_r = b_hid[tid];
        float bsc = b_score[0];
        S->hL[tid] = ((const unsigned*)hslab)[(size_t)b * 256 + tid];
        float cs0 = c_cur[b * H_ + 2 * tid], cs1 = c_cur[b * H_ + 2 * tid + 1];
        const f16x4* wp4 = (const f16x4*)Whidp;
        int wv = tid >> 6, ln = tid & 63;
        __syncthreads();

        for (int t = 0; t < T_; ++t) {
            // ---- ea = h @ W_hid + b_hid (k-quad 8B loads, 2x fdot2) ----
            {
                float acc = bhid_r;
#pragma unroll 16
                for (int k4 = 0; k4 < 128; ++k4) {
                    union { f16x4 v; f16x2 p[2]; } w;
                    w.v = wp4[(size_t)k4 * 256 + tid];
                    union { unsigned u; f16x2 v; } h0, h1;
                    h0.u = S->hL[2 * k4];
                    h1.u = S->hL[2 * k4 + 1];
#ifdef HAS_FDOT2
                    acc = __builtin_amdgcn_fdot2(w.p[0], h0.v, acc, false);
                    acc = __builtin_amdgcn_fdot2(w.p[1], h1.v, acc, false);
#else
                    acc += (float)w.p[0].x * (float)h0.v.x + (float)w.p[0].y * (float)h0.v.y;
                    acc += (float)w.p[1].x * (float)h1.v.x + (float)w.p[1].y * (float)h1.v.y;
#endif
                }
                S->ea[tid] = acc;
            }
            __syncthreads();
            // ---- scores ----
            for (int l = wv; l < L_; l += 4) {
                float p = 0.f;
#pragma unroll
                for (int q = 0; q < 4; ++q) {
                    int j = ln + q * 64;
                    p += tanh_f(S->fp[l][j] + S->ea[j]) * S->ws[j];
                }
#pragma unroll
                for (int off = 32; off > 0; off >>= 1) p += __shfl_xor(p, off);
                if (ln == 0) S->sc[l] = p;
            }
            __syncthreads();
            // ---- softmax (wave 0) ----
            if (tid < 64) {
                float v = (tid < L_) ? S->sc[tid] + bsc : -3.4e38f;
                float m = v;
#pragma unroll
                for (int off = 32; off > 0; off >>= 1) m = fmaxf(m, __shfl_xor(m, off));
                float e = (tid < L_) ? __expf(v - m) : 0.f;
                float s = e;
#pragma unroll
                for (int off = 32; off > 0; off >>= 1) s += __shfl_xor(s, off);
                if (tid < L_) {
                    float al = e / s;
                    S->alpha[tid] = al;
                    out_alpha[((size_t)b * T_ + t) * L_ + tid] = al;
                }
            }
            __syncthreads();
            // ---- ep prefetch (independent; hides under ctx reduction) ----
            f16x8 ep = *(const f16x8*)&embP[((size_t)b * T_ + t) * G4 + 8 * tid];
            // ---- ctx = sum_l alpha_l * feats[b,l,:]; publish ----
            {
                float c0 = 0.f, c1 = 0.f;
#pragma unroll 7
                for (int l = 0; l < L_; ++l) {
                    float a = S->alpha[l];
                    union { unsigned u; f16x2 v; } fv;
                    fv.u = S->fe[l * 256 + tid];
                    c0 += a * (float)fv.v.x;
                    c1 += a * (float)fv.v.y;
                }
                union { f16 h[2]; unsigned u; } pk;
                pk.h[0] = (f16)c0; pk.h[1] = (f16)c1;
                ASTORE32((unsigned*)ctxslab + ((size_t)t * B_ + b) * 256 + tid, pk.u);
            }
            __syncthreads();
            if (tid == 0) ASTORE32(&ctxflag[b * SLOT], (unsigned)(t + 1));
            // ---- wait combined recurrent matmul, pointwise ----
            wait_n(gemmflag, NG, (unsigned)(t + 1));
            {
                f16x8 hw = *(const f16x8*)&hwcslab[((size_t)t * B_ + b) * G4 + 8 * tid];
                float gA[8];
#pragma unroll
                for (int i = 0; i < 8; ++i) gA[i] = (float)hw[i] + (float)ep[i];
                float cn0 = sigm(gA[1]) * cs0 + sigm(gA[0]) * tanh_f(gA[2]);
                float cn1 = sigm(gA[5]) * cs1 + sigm(gA[4]) * tanh_f(gA[6]);
                float hn0 = sigm(gA[3]) * tanh_f(cn0);
                float hn1 = sigm(gA[7]) * tanh_f(cn1);
                cs0 = cn0; cs1 = cn1;
                union { f16 h[2]; unsigned u; } pk;
                pk.h[0] = (f16)hn0; pk.h[1] = (f16)hn1;
                S->hL[tid] = pk.u;
                ASTORE32((unsigned*)hslab + ((size_t)(t + 1) * B_ + b) * 256 + tid, pk.u);
            }
            __syncthreads();
            if (tid == 0)
                ASTORE32(&gateflag[b * SLOT], (unsigned)(t + 2));
        }
    } else if (bid < 64 + NG) {
        // ======== gemm block g: permuted cols [32g,32g+32) = hidden [8g,8g+8) ========
        int g = bid - 64;
        GemmSm* S = (GemmSm*)smraw;
        // one-time raw-f32 staging with inline transpose
        for (int rowbase = 0; rowbase < 512; rowbase += 256) {
            int k = rowbase + tid;
            const float* wh = W_hh + (size_t)k * G4 + 8 * g;
            const float* wi = W_ih + (size_t)(E_ + k) * G4 + 8 * g;
            int ch = k >> 3, j = k & 7;
#pragma unroll
            for (int q = 0; q < 4; ++q) {
                float4 v0 = *(const float4*)(wh + q * 512);
                float4 v1 = *(const float4*)(wh + q * 512 + 4);
                float4 u0 = *(const float4*)(wi + q * 512);
                float4 u1 = *(const float4*)(wi + q * 512 + 4);
                float vv[8] = {v0.x,v0.y,v0.z,v0.w, v1.x,v1.y,v1.z,v1.w};
                float uu[8] = {u0.x,u0.y,u0.z,u0.w, u1.x,u1.y,u1.z,u1.w};
#pragma unroll
                for (int d = 0; d < 8; ++d) {
                    int r = d * 4 + q;
                    S->w[r][((ch ^ (r & 7)) << 3) + j]  = (f16)vv[d];
                    S->w2[r][((ch ^ (r & 7)) << 3) + j] = (f16)uu[d];
                }
            }
        }
        int wvv = tid >> 6, lane = tid & 63;
        int frow = lane & 15, q = lane >> 4, sw = frow & 7, rq = q * 4;
        int mb = (wvv >> 1) * 32, c16 = (wvv & 1) * 16;
        int bo = tid >> 2, cq = (tid & 3) * 8;
        __syncthreads();

        for (int t = 0; t < T_; ++t) {
            if (t) wait_n(gateflag, 64, (unsigned)(t + 1));
            {
                const f16* hsrc = hslab + (size_t)t * B_ * H_;
#pragma unroll
                for (int i = 0; i < 16; ++i) {
                    int idx = i * 256 + tid;
                    int r = idx >> 6, ch = idx & 63;
                    *(f16x8*)&S->u.hs[r][(ch ^ (r & 7)) * 8] =
                        *(const f16x8*)&hsrc[(size_t)r * H_ + ch * 8];
                }
            }
            __syncthreads();
            f32x4 a4[2];
            a4[0][0]=0.f; a4[0][1]=0.f; a4[0][2]=0.f; a4[0][3]=0.f;
            a4[1][0]=0.f; a4[1][1]=0.f; a4[1][2]=0.f; a4[1][3]=0.f;
#pragma unroll
            for (int kk = 0; kk < 16; ++kk) {
                int ch = ((kk * 4 + q) ^ sw) * 8;
                f16x8 bv = *(f16x8*)&S->w[c16 + frow][ch];
                f16x8 av0 = *(f16x8*)&S->u.hs[mb + frow][ch];
                f16x8 av1 = *(f16x8*)&S->u.hs[mb + 16 + frow][ch];
                a4[0] = __builtin_amdgcn_mfma_f32_16x16x32_f16(av0, bv, a4[0], 0, 0, 0);
                a4[1] = __builtin_amdgcn_mfma_f32_16x16x32_f16(av1, bv, a4[1], 0, 0, 0);
            }
            wait_n(ctxflag, 64, (unsigned)(t + 1));
            {
                const f16* csrc = ctxslab + (size_t)t * B_ * F_;
#pragma unroll
                for (int i = 0; i < 16; ++i) {
                    int idx = i * 256 + tid;
                    int r = idx >> 6, ch = idx & 63;
                    *(f16x8*)&S->u.hs[r][(ch ^ (r & 7)) * 8] =
                        *(const f16x8*)&csrc[(size_t)r * F_ + ch * 8];
                }
            }
            __syncthreads();
#pragma unroll
            for (int kk = 0; kk < 16; ++kk) {
                int ch = ((kk * 4 + q) ^ sw) * 8;
                f16x8 bv = *(f16x8*)&S->w2[c16 + frow][ch];
                f16x8 av0 = *(f16x8*)&S->u.hs[mb + frow][ch];
                f16x8 av1 = *(f16x8*)&S->u.hs[mb + 16 + frow][ch];
                a4[0] = __builtin_amdgcn_mfma_f32_16x16x32_f16(av0, bv, a4[0], 0, 0, 0);
                a4[1] = __builtin_amdgcn_mfma_f32_16x16x32_f16(av1, bv, a4[1], 0, 0, 0);
            }
            __syncthreads();
#pragma unroll
            for (int mi = 0; mi < 2; ++mi)
#pragma unroll
                for (int r = 0; r < 4; ++r)
                    S->u.hwT16[mb + mi * 16 + rq + r][c16 + frow] = (f16)a4[mi][r];
            __syncthreads();
            {
                f16* dst = hwcslab + ((size_t)t * B_ + bo) * G4 + 32 * g + cq;
                union { f16 h[4]; ull u; } pk0, pk1;
                *(f16x4*)pk0.h = *(f16x4*)&S->u.hwT16[bo][cq];
                *(f16x4*)pk1.h = *(f16x4*)&S->u.hwT16[bo][cq + 4];
                ASTORE64(dst, pk0.u);
                ASTORE64(dst + 4, pk1.u);
            }
            __syncthreads();
            if (tid == 0)
                ASTORE32(&gemmflag[g * SLOT], (unsigned)(t + 1));
        }
    } else {
        // ======== logit block: W_out cols [nt*256, nt*256+256) ========
        int nt = bid - 64 - NG;
        int n0 = nt * 256;
        LogSm* S = (LogSm*)smraw;
        int wvv = tid >> 6, lane = tid & 63;
        int frow = lane & 15, q = lane >> 4, sw = frow & 7, rq = q * 4;

        // ---- lazy transpose of own W_out slice (f32 -> f16 [col][k]) ----
        {
            float (*ls)[33] = (float(*)[33])smraw;
            int rr = tid >> 3, cs = (tid & 7) * 4;
            int cr = tid >> 3, rs = (tid & 7) * 4;
            for (int c0 = 0; c0 < 256; c0 += 32)
                for (int k0 = 0; k0 < 512; k0 += 32) {
                    float4 v = *(const float4*)&W_out[(size_t)(k0 + rr) * V_ + n0 + c0 + cs];
                    __syncthreads();
                    ls[rr][cs] = v.x; ls[rr][cs + 1] = v.y; ls[rr][cs + 2] = v.z; ls[rr][cs + 3] = v.w;
                    __syncthreads();
                    f16x4 o = {(f16)ls[rs][cr], (f16)ls[rs + 1][cr],
                               (f16)ls[rs + 2][cr], (f16)ls[rs + 3][cr]};
                    *(f16x4*)&WoutT[(size_t)(n0 + c0 + cr) * 512 + k0 + rs] = o;
                }
            __syncthreads();
        }

        for (int tc = 0; tc < T_ / 2; ++tc) {
            wait_n_slow(gateflag, 64, (unsigned)(2 * tc + 3));
            {
                const f16* hsrc = hslab + (size_t)(2 * tc + 1) * B_ * H_;
#pragma unroll
                for (int i = 0; i < 32; ++i) {
                    int idx = i * 256 + tid;
                    int r = idx >> 6, ch = idx & 63;
                    *(f16x8*)&S->hs[r][(ch ^ (r & 7)) * 8] =
                        *(const f16x8*)&hsrc[(size_t)r * H_ + ch * 8];
                }
            }
            __syncthreads();
            f32x4 acc[8][4];
#pragma unroll
            for (int mi = 0; mi < 8; ++mi)
#pragma unroll
                for (int ni = 0; ni < 4; ++ni) { acc[mi][ni][0]=0.f; acc[mi][ni][1]=0.f; acc[mi][ni][2]=0.f; acc[mi][ni][3]=0.f; }
#pragma unroll 2
            for (int kk = 0; kk < 16; ++kk) {
                int ch = ((kk * 4 + q) ^ sw) * 8;
                f16x8 av[8], bv[4];
#pragma unroll
                for (int mi = 0; mi < 8; ++mi)
                    av[mi] = *(f16x8*)&S->hs[mi * 16 + frow][ch];
#pragma unroll
                for (int ni = 0; ni < 4; ++ni)
                    bv[ni] = *(const f16x8*)&WoutT[(size_t)(n0 + wvv * 64 + ni * 16 + frow) * 512 + kk * 32 + q * 8];
#pragma unroll
                for (int mi = 0; mi < 8; ++mi)
#pragma unroll
                    for (int ni = 0; ni < 4; ++ni)
                        acc[mi][ni] = __builtin_amdgcn_mfma_f32_16x16x32_f16(av[mi], bv[ni], acc[mi][ni], 0, 0, 0);
            }
#pragma unroll
            for (int ni = 0; ni < 4; ++ni) {
                int cc = n0 + wvv * 64 + ni * 16 + frow;
                float badd = b_out[cc];
#pragma unroll
                for (int mi = 0; mi < 8; ++mi)
#pragma unroll
                    for (int r = 0; r < 4; ++r) {
                        int rr = mi * 16 + rq + r;
                        int tt = 2 * tc + (rr >> 6), bb2 = rr & 63;
                        preds[((size_t)bb2 * T_ + tt) * V_ + cc] = acc[mi][ni][r] + badd;
                    }
            }
            __syncthreads();
        }
    }
}

// ================================================================ launch
extern "C" void kernel_launch(void* const* d_in, const int* in_sizes, int n_in,
                              void* d_out, int out_size, void* d_ws, size_t ws_size,
                              hipStream_t stream) {
    const float* image_feats = (const float*)d_in[0];
    const int*   caption     = (const int*)d_in[1];
    const float* embedding   = (const float*)d_in[2];
    const float* W_init_h    = (const float*)d_in[3];
    const float* b_init_h    = (const float*)d_in[4];
    const float* W_init_c    = (const float*)d_in[5];
    const float* b_init_c    = (const float*)d_in[6];
    const float* W_feat      = (const float*)d_in[7];
    const float* b_feat      = (const float*)d_in[8];
    const float* W_hid       = (const float*)d_in[9];
    const float* b_hid       = (const float*)d_in[10];
    const float* W_score     = (const float*)d_in[11];
    const float* b_score     = (const float*)d_in[12];
    const float* W_ih        = (const float*)d_in[13];
    const float* b_ih        = (const float*)d_in[14];
    const float* W_hh        = (const float*)d_in[15];
    const float* b_hh        = (const float*)d_in[16];
    const float* W_out       = (const float*)d_in[17];
    const float* b_out       = (const float*)d_in[18];

    float* preds = (float*)d_out;                                   // (B,T,V)
    float* out_alpha = preds + (size_t)B_ * T_ * V_;                // (B,T,L)

    size_t off = 0;
    char* base = (char*)d_ws;
    auto carve = [&](size_t bytes) {
        void* p = base + off;
        off += (bytes + 255) & ~(size_t)255;
        return p;
    };
    f16* embP       = (f16*)carve((size_t)B_ * T_ * G4 * 2);        // 8.4 MB
    float* featproj = (float*)carve((size_t)B_ * L_ * A_ * 4);      // 3.2 MB
    float* c_cur    = (float*)carve((size_t)B_ * H_ * 4);
    f16* hslab      = (f16*)carve((size_t)(T_ + 1) * B_ * H_ * 2);  // 2.1 MB
    f16* ctxslab    = (f16*)carve((size_t)T_ * B_ * F_ * 2);        // 2.1 MB
    f16* hwcslab    = (f16*)carve((size_t)T_ * B_ * G4 * 2);        // 8 MB
    unsigned* flags = (unsigned*)carve((64 + 64 + NG) * SLOT * 4);
    f16* WoutT      = (f16*)carve((size_t)V_ * H_ * 2);             // 32.8 MB
    f16* Whidp      = (f16*)carve((size_t)H_ * A_ * 2);
    unsigned* gateflag = flags;
    unsigned* ctxflag  = flags + 64 * SLOT;
    unsigned* gemmflag = flags + 128 * SLOT;
    (void)ws_size; (void)in_sizes; (void)n_in; (void)out_size;

    // 1) reset flags
    hipMemsetAsync(flags, 0, (64 + 64 + NG) * SLOT * 4, stream);
    // 2) fused prologue: embP GEMM (raw gather/transpose) + Whidp + init + featproj
    hipLaunchKernelGGL(k_prep, dim3(NB_EMBG + NB_Q + NB_INIT + NB_FP), dim3(256), 0, stream,
                       image_feats, caption, embedding,
                       W_init_h, b_init_h, W_init_c, b_init_c,
                       W_feat, b_feat, W_hid, W_ih, b_ih, b_hh,
                       embP, Whidp, hslab, c_cur, featproj);
    // 3) persistent recurrence + shadowed logits (253 blocks, co-resident)
    hipLaunchKernelGGL(k_steps, dim3(64 + NG + NLOG), dim3(256), 0, stream,
                       W_hh, W_ih, Whidp, featproj, image_feats, b_hid,
                       W_score, b_score, embP, c_cur,
                       hslab, ctxslab, hwcslab,
                       W_out, WoutT, b_out, preds, out_alpha,
                       gateflag, ctxflag, gemmflag);
}